// Round 1
// baseline (2807.372 us; speedup 1.0000x reference)
//
#include <hip/hip_runtime.h>
#include <math.h>

#define NTOK 73728
#define DVQ 64
#define KCODES 1024

__device__ __forceinline__ float gelu_f(float x) {
    return 0.5f * x * (1.0f + erff(x * 0.70710678118654752440f));
}

// ---------------- codebook norms in f64 ----------------
__global__ void k_norms(const float* __restrict__ cb_s, const float* __restrict__ cb_x,
                        double* __restrict__ cn_s, double* __restrict__ cn_x) {
    int i = blockIdx.x * blockDim.x + threadIdx.x;
    if (i >= 2 * KCODES) return;
    const float* cb = (i < KCODES) ? cb_s : cb_x;
    double* cn = (i < KCODES) ? cn_s : cn_x;
    int c = i & (KCODES - 1);
    double s = 0.0;
    #pragma unroll 8
    for (int k = 0; k < DVQ; ++k) { double v = (double)cb[c * DVQ + k]; s += v * v; }
    cn[c] = s;
}

// ---------------- spectral encoder: cubes -> z_e_s ----------------
__global__ void __launch_bounds__(64) k_spec_enc(
    const float* __restrict__ cubes,
    const float* __restrict__ w1, const float* __restrict__ b1,
    const float* __restrict__ w2, const float* __restrict__ b2,
    const float* __restrict__ fcw, const float* __restrict__ fcb,
    float* __restrict__ z_out)
{
    __shared__ float h[128][64];   // h1[c*8+l] per-thread column, 32 KB
    int tid = threadIdx.x;
    int n = blockIdx.x * 64 + tid;
    const float* cu = cubes + (size_t)n * 72;
    float spec[8];
    #pragma unroll
    for (int f = 0; f < 8; ++f) {
        float s = 0.f;
        #pragma unroll
        for (int k = 0; k < 9; ++k) s += cu[f * 9 + k];
        spec[f] = s * (1.0f / 9.0f);
    }
    // conv1d 1->16, same pad, gelu
    for (int c = 0; c < 16; ++c) {
        float wa = w1[c * 3 + 0], wb = w1[c * 3 + 1], wc = w1[c * 3 + 2], bb = b1[c];
        #pragma unroll
        for (int l = 0; l < 8; ++l) {
            float v = bb + wb * spec[l];
            if (l > 0) v += wa * spec[l - 1];
            if (l < 7) v += wc * spec[l + 1];
            h[c * 8 + l][tid] = gelu_f(v);
        }
    }
    // conv1d 16->16 gelu, fused fc accumulate
    float z[64];
    #pragma unroll
    for (int d = 0; d < 64; ++d) z[d] = fcb[d];
    for (int c = 0; c < 16; ++c) {
        #pragma unroll
        for (int l = 0; l < 8; ++l) {
            float v = b2[c];
            for (int ci = 0; ci < 16; ++ci) {
                const float* w = w2 + (c * 16 + ci) * 3;
                if (l > 0) v = fmaf(w[0], h[ci * 8 + l - 1][tid], v);
                v = fmaf(w[1], h[ci * 8 + l][tid], v);
                if (l < 7) v = fmaf(w[2], h[ci * 8 + l + 1][tid], v);
            }
            v = gelu_f(v);
            const int e = c * 8 + l;
            #pragma unroll
            for (int d = 0; d < 64; ++d) z[d] = fmaf(fcw[d * 128 + e], v, z[d]);
        }
    }
    float* zo = z_out + (size_t)n * 64;
    #pragma unroll
    for (int d = 0; d < 64; ++d) zo[d] = z[d];
}

// ---------------- spatial encoder: cubes -> z_e_x ----------------
__global__ void __launch_bounds__(64) k_spat_enc(
    const float* __restrict__ cubes,
    const float* __restrict__ w1, const float* __restrict__ b1,
    const float* __restrict__ w2, const float* __restrict__ b2,
    const float* __restrict__ fcw, const float* __restrict__ fcb,
    float* __restrict__ z_out)
{
    __shared__ float h[144][64];   // h1[c*9+i*3+j], 36 KB
    int tid = threadIdx.x;
    int n = blockIdx.x * 64 + tid;
    const float* cu = cubes + (size_t)n * 72;
    float sin_[72];
    #pragma unroll
    for (int t = 0; t < 72; ++t) sin_[t] = cu[t];
    // conv2d 8->16 same pad, gelu
    for (int c = 0; c < 16; ++c) {
        float bb = b1[c];
        #pragma unroll
        for (int i = 0; i < 3; ++i) {
            #pragma unroll
            for (int j = 0; j < 3; ++j) {
                float v = bb;
                #pragma unroll
                for (int ci = 0; ci < 8; ++ci) {
                    #pragma unroll
                    for (int di = 0; di < 3; ++di) {
                        int ii = i + di - 1; if (ii < 0 || ii > 2) continue;
                        #pragma unroll
                        for (int dj = 0; dj < 3; ++dj) {
                            int jj = j + dj - 1; if (jj < 0 || jj > 2) continue;
                            v = fmaf(w1[((c * 8 + ci) * 3 + di) * 3 + dj], sin_[ci * 9 + ii * 3 + jj], v);
                        }
                    }
                }
                h[c * 9 + i * 3 + j][tid] = gelu_f(v);
            }
        }
    }
    // conv2d 16->16 gelu, fused fc
    float z[64];
    #pragma unroll
    for (int d = 0; d < 64; ++d) z[d] = fcb[d];
    for (int c = 0; c < 16; ++c) {
        #pragma unroll
        for (int i = 0; i < 3; ++i) {
            #pragma unroll
            for (int j = 0; j < 3; ++j) {
                float v = b2[c];
                for (int ci = 0; ci < 16; ++ci) {
                    #pragma unroll
                    for (int di = 0; di < 3; ++di) {
                        int ii = i + di - 1; if (ii < 0 || ii > 2) continue;
                        #pragma unroll
                        for (int dj = 0; dj < 3; ++dj) {
                            int jj = j + dj - 1; if (jj < 0 || jj > 2) continue;
                            v = fmaf(w2[((c * 16 + ci) * 3 + di) * 3 + dj], h[ci * 9 + ii * 3 + jj][tid], v);
                        }
                    }
                }
                v = gelu_f(v);
                const int e = c * 9 + i * 3 + j;
                #pragma unroll
                for (int d = 0; d < 64; ++d) z[d] = fmaf(fcw[d * 144 + e], v, z[d]);
            }
        }
    }
    float* zo = z_out + (size_t)n * 64;
    #pragma unroll
    for (int d = 0; d < 64; ++d) zo[d] = z[d];
}

// ---------------- VQ: argmin over codebook, gather, losses ----------------
__global__ void __launch_bounds__(256) k_vq(
    float* __restrict__ emb,            // in: z_e, out: z_q
    const float* __restrict__ cb,
    const double* __restrict__ cn,
    float* __restrict__ idx_out,
    int* __restrict__ hist,
    double* __restrict__ partial)
{
    __shared__ float cbt[128 * 64];     // 32 KB code tile
    __shared__ double cnt[128];
    __shared__ int lh[1024];
    __shared__ double wred[4];
    int tid = threadIdx.x;
    int n = blockIdx.x * 256 + tid;
    for (int t = tid; t < 1024; t += 256) lh[t] = 0;
    float z[64];
    float* ze = emb + (size_t)n * 64;
    #pragma unroll
    for (int k = 0; k < 64; ++k) z[k] = ze[k];
    double best = 1e300; int bi = 0;
    for (int c0 = 0; c0 < KCODES; c0 += 128) {
        __syncthreads();
        const float4* src = (const float4*)(cb + (size_t)c0 * 64);
        float4* dst = (float4*)cbt;
        for (int t = tid; t < 128 * 16; t += 256) dst[t] = src[t];
        if (tid < 128) cnt[tid] = cn[c0 + tid];
        __syncthreads();
        for (int c = 0; c < 128; ++c) {
            const float* cr = cbt + c * 64;
            float dot = 0.f;
            #pragma unroll
            for (int k = 0; k < 64; k += 4) {
                float4 q = *(const float4*)(cr + k);
                dot = fmaf(z[k + 0], q.x, dot);
                dot = fmaf(z[k + 1], q.y, dot);
                dot = fmaf(z[k + 2], q.z, dot);
                dot = fmaf(z[k + 3], q.w, dot);
            }
            double d = cnt[c] - 2.0 * (double)dot;
            if (d < best) { best = d; bi = c0 + c; }   // strict < : first-index tie-break
        }
    }
    idx_out[n] = (float)bi;
    const float* cq = cb + (size_t)bi * 64;
    float vsum = 0.f;
    #pragma unroll
    for (int k = 0; k < 64; ++k) {
        float q = cq[k];
        float diff = z[k] - q;
        vsum = fmaf(diff, diff, vsum);
        ze[k] = q;                       // straight-through == z_q in f64 ref
    }
    atomicAdd(&lh[bi], 1);
    double s = (double)vsum;
    #pragma unroll
    for (int o = 32; o > 0; o >>= 1) s += __shfl_down(s, o);
    if ((tid & 63) == 0) wred[tid >> 6] = s;
    __syncthreads();
    if (tid == 0) partial[blockIdx.x] = wred[0] + wred[1] + wred[2] + wred[3];
    for (int t = tid; t < 1024; t += 256) if (lh[t] > 0) atomicAdd(&hist[t], lh[t]);
}

// ---------------- spectral decoder + recon loss ----------------
__global__ void __launch_bounds__(64) k_spec_dec(
    const float* __restrict__ emb, const float* __restrict__ cubes,
    const float* __restrict__ dfcw, const float* __restrict__ dfcb,
    const float* __restrict__ w1, const float* __restrict__ b1,
    const float* __restrict__ w2, const float* __restrict__ b2,
    double* __restrict__ partial)
{
    __shared__ float t1[128][64];
    __shared__ float h2[128][64];
    int tid = threadIdx.x;
    int n = blockIdx.x * 64 + tid;
    float z[64];
    const float* zq = emb + (size_t)n * 64;
    #pragma unroll
    for (int d = 0; d < 64; ++d) z[d] = zq[d];
    for (int o = 0; o < 128; ++o) {
        float v = dfcb[o];
        #pragma unroll
        for (int d = 0; d < 64; ++d) v = fmaf(dfcw[o * 64 + d], z[d], v);
        t1[o][tid] = v;
    }
    for (int c = 0; c < 16; ++c) {
        #pragma unroll
        for (int l = 0; l < 8; ++l) {
            float v = b1[c];
            for (int ci = 0; ci < 16; ++ci) {
                const float* w = w1 + (c * 16 + ci) * 3;
                if (l > 0) v = fmaf(w[0], t1[ci * 8 + l - 1][tid], v);
                v = fmaf(w[1], t1[ci * 8 + l][tid], v);
                if (l < 7) v = fmaf(w[2], t1[ci * 8 + l + 1][tid], v);
            }
            h2[c * 8 + l][tid] = gelu_f(v);
        }
    }
    const float* cu = cubes + (size_t)n * 72;
    float acc = 0.f;
    #pragma unroll
    for (int l = 0; l < 8; ++l) {
        float v = b2[0];
        for (int ci = 0; ci < 16; ++ci) {
            const float* w = w2 + ci * 3;
            if (l > 0) v = fmaf(w[0], h2[ci * 8 + l - 1][tid], v);
            v = fmaf(w[1], h2[ci * 8 + l][tid], v);
            if (l < 7) v = fmaf(w[2], h2[ci * 8 + l + 1][tid], v);
        }
        float s = 0.f;
        #pragma unroll
        for (int k = 0; k < 9; ++k) s += cu[l * 9 + k];
        s *= (1.0f / 9.0f);
        float diff = v - s;
        acc = fmaf(diff, diff, acc);
    }
    double sd = (double)acc;
    #pragma unroll
    for (int o = 32; o > 0; o >>= 1) sd += __shfl_down(sd, o);
    if (tid == 0) partial[blockIdx.x] = sd;
}

// ---------------- spatial decoder + recon loss ----------------
__global__ void __launch_bounds__(64) k_spat_dec(
    const float* __restrict__ emb, const float* __restrict__ cubes,
    const float* __restrict__ dfcw, const float* __restrict__ dfcb,
    const float* __restrict__ w1, const float* __restrict__ b1,
    const float* __restrict__ w2, const float* __restrict__ b2,
    double* __restrict__ partial)
{
    __shared__ float t1[144][64];
    __shared__ float h2[144][64];
    int tid = threadIdx.x;
    int n = blockIdx.x * 64 + tid;
    float z[64];
    const float* zq = emb + (size_t)n * 64;
    #pragma unroll
    for (int d = 0; d < 64; ++d) z[d] = zq[d];
    for (int o = 0; o < 144; ++o) {
        float v = dfcb[o];
        #pragma unroll
        for (int d = 0; d < 64; ++d) v = fmaf(dfcw[o * 64 + d], z[d], v);
        t1[o][tid] = v;
    }
    for (int c = 0; c < 16; ++c) {
        #pragma unroll
        for (int i = 0; i < 3; ++i) {
            #pragma unroll
            for (int j = 0; j < 3; ++j) {
                float v = b1[c];
                for (int ci = 0; ci < 16; ++ci) {
                    #pragma unroll
                    for (int di = 0; di < 3; ++di) {
                        int ii = i + di - 1; if (ii < 0 || ii > 2) continue;
                        #pragma unroll
                        for (int dj = 0; dj < 3; ++dj) {
                            int jj = j + dj - 1; if (jj < 0 || jj > 2) continue;
                            v = fmaf(w1[((c * 16 + ci) * 3 + di) * 3 + dj], t1[ci * 9 + ii * 3 + jj][tid], v);
                        }
                    }
                }
                h2[c * 9 + i * 3 + j][tid] = gelu_f(v);
            }
        }
    }
    const float* cu = cubes + (size_t)n * 72;
    float acc = 0.f;
    for (int co = 0; co < 8; ++co) {
        #pragma unroll
        for (int i = 0; i < 3; ++i) {
            #pragma unroll
            for (int j = 0; j < 3; ++j) {
                float v = b2[co];
                for (int ci = 0; ci < 16; ++ci) {
                    #pragma unroll
                    for (int di = 0; di < 3; ++di) {
                        int ii = i + di - 1; if (ii < 0 || ii > 2) continue;
                        #pragma unroll
                        for (int dj = 0; dj < 3; ++dj) {
                            int jj = j + dj - 1; if (jj < 0 || jj > 2) continue;
                            v = fmaf(w2[((co * 16 + ci) * 3 + di) * 3 + dj], h2[ci * 9 + ii * 3 + jj][tid], v);
                        }
                    }
                }
                float diff = v - cu[co * 9 + i * 3 + j];
                acc = fmaf(diff, diff, acc);
            }
        }
    }
    double sd = (double)acc;
    #pragma unroll
    for (int o = 32; o > 0; o >>= 1) sd += __shfl_down(sd, o);
    if (tid == 0) partial[blockIdx.x] = sd;
}

// ---------------- finalize scalars ----------------
__global__ void __launch_bounds__(256) k_final(
    const double* __restrict__ p_vq_s, const double* __restrict__ p_vq_x,
    const double* __restrict__ p_rec_s, const double* __restrict__ p_rec_x,
    const int* __restrict__ hist_s, const int* __restrict__ hist_x,
    const int* __restrict__ rr,
    float* __restrict__ outscal)
{
    __shared__ double wred[4];
    int tid = threadIdx.x;
    auto bred = [&](double v) -> double {
        #pragma unroll
        for (int o = 32; o > 0; o >>= 1) v += __shfl_down(v, o);
        __syncthreads();
        if ((tid & 63) == 0) wred[tid >> 6] = v;
        __syncthreads();
        return wred[0] + wred[1] + wred[2] + wred[3];
    };
    double a;
    a = 0; for (int t = tid; t < 288; t += 256) a += p_vq_s[t];
    double vq_s = bred(a);
    a = 0; for (int t = tid; t < 288; t += 256) a += p_vq_x[t];
    double vq_x = bred(a);
    a = 0; for (int t = tid; t < 1152; t += 256) a += p_rec_s[t];
    double rec_s = bred(a);
    a = 0; for (int t = tid; t < 1152; t += 256) a += p_rec_x[t];
    double rec_x = bred(a);
    a = 0;
    for (int t = tid; t < 1024; t += 256) {
        double c = (double)hist_s[t];
        if (c > 0.0) { double p = c / (double)NTOK; a += p * log(p + 1e-10); }
    }
    double ent_s = bred(a);
    a = 0;
    for (int t = tid; t < 1024; t += 256) {
        double c = (double)hist_x[t];
        if (c > 0.0) { double p = c / (double)NTOK; a += p * log(p + 1e-10); }
    }
    double ent_x = bred(a);
    if (tid == 0) {
        double total = 0.25 * (vq_s / 4718592.0 + vq_x / 4718592.0);
        double rec = (rr[0] != 0) ? (rec_s / 589824.0 + rec_x / 5308416.0) : 0.0;
        outscal[0] = (float)total;
        outscal[1] = (float)exp(-ent_s);
        outscal[2] = (float)exp(-ent_x);
        outscal[3] = (float)rec;
    }
}

extern "C" void kernel_launch(void* const* d_in, const int* in_sizes, int n_in,
                              void* d_out, int out_size, void* d_ws, size_t ws_size,
                              hipStream_t stream)
{
    const float* cubes  = (const float*)d_in[0];
    const float* s_w1   = (const float*)d_in[1];
    const float* s_b1   = (const float*)d_in[2];
    const float* s_w2   = (const float*)d_in[3];
    const float* s_b2   = (const float*)d_in[4];
    const float* s_fcw  = (const float*)d_in[5];
    const float* s_fcb  = (const float*)d_in[6];
    const float* cb_s   = (const float*)d_in[7];
    const float* s_dfcw = (const float*)d_in[8];
    const float* s_dfcb = (const float*)d_in[9];
    const float* s_dw1  = (const float*)d_in[10];
    const float* s_db1  = (const float*)d_in[11];
    const float* s_dw2  = (const float*)d_in[12];
    const float* s_db2  = (const float*)d_in[13];
    const float* x_w1   = (const float*)d_in[14];
    const float* x_b1   = (const float*)d_in[15];
    const float* x_w2   = (const float*)d_in[16];
    const float* x_b2   = (const float*)d_in[17];
    const float* x_fcw  = (const float*)d_in[18];
    const float* x_fcb  = (const float*)d_in[19];
    const float* cb_x   = (const float*)d_in[20];
    const float* x_dfcw = (const float*)d_in[21];
    const float* x_dfcb = (const float*)d_in[22];
    const float* x_dw1  = (const float*)d_in[23];
    const float* x_db1  = (const float*)d_in[24];
    const float* x_dw2  = (const float*)d_in[25];
    const float* x_db2  = (const float*)d_in[26];
    const int*   rr     = (const int*)d_in[27];

    float* out   = (float*)d_out;
    float* emb_s = out;                       // [N,64]
    float* emb_x = out + 4718592;             // [N,64]
    float* kidx  = out + 9437184;             // [N]
    float* midx  = out + 9510912;             // [N]
    float* scal  = out + 9584640;             // [4]

    char* ws = (char*)d_ws;
    int*    hist_s  = (int*)(ws + 0);
    int*    hist_x  = (int*)(ws + 4096);
    double* cn_s    = (double*)(ws + 8192);
    double* cn_x    = (double*)(ws + 16384);
    double* p_vq_s  = (double*)(ws + 24576);  // 288
    double* p_vq_x  = (double*)(ws + 26880);  // 288
    double* p_rec_s = (double*)(ws + 29184);  // 1152
    double* p_rec_x = (double*)(ws + 38400);  // 1152  (end 47616)

    hipMemsetAsync(d_ws, 0, 8192, stream);    // zero histograms
    k_norms<<<16, 128, 0, stream>>>(cb_s, cb_x, cn_s, cn_x);
    k_spec_enc<<<1152, 64, 0, stream>>>(cubes, s_w1, s_b1, s_w2, s_b2, s_fcw, s_fcb, emb_s);
    k_spat_enc<<<1152, 64, 0, stream>>>(cubes, x_w1, x_b1, x_w2, x_b2, x_fcw, x_fcb, emb_x);
    k_vq<<<288, 256, 0, stream>>>(emb_s, cb_s, cn_s, kidx, hist_s, p_vq_s);
    k_vq<<<288, 256, 0, stream>>>(emb_x, cb_x, cn_x, midx, hist_x, p_vq_x);
    k_spec_dec<<<1152, 64, 0, stream>>>(emb_s, cubes, s_dfcw, s_dfcb, s_dw1, s_db1, s_dw2, s_db2, p_rec_s);
    k_spat_dec<<<1152, 64, 0, stream>>>(emb_x, cubes, x_dfcw, x_dfcb, x_dw1, x_db1, x_dw2, x_db2, p_rec_x);
    k_final<<<1, 256, 0, stream>>>(p_vq_s, p_vq_x, p_rec_s, p_rec_x, hist_s, hist_x, rr, scal);
}

// Round 2
// 2669.329 us; speedup vs baseline: 1.0517x; 1.0517x over previous
//
#include <hip/hip_runtime.h>
#include <math.h>

#define NTOK 73728

__device__ __forceinline__ float gelu_f(float x) {
    return 0.5f * x * (1.0f + erff(x * 0.70710678118654752440f));
}

// ---------------- codebook norms in f64 ----------------
__global__ void k_norms(const float* __restrict__ cb_s, const float* __restrict__ cb_x,
                        double* __restrict__ cn_s, double* __restrict__ cn_x) {
    int i = blockIdx.x * blockDim.x + threadIdx.x;
    if (i >= 2048) return;
    const float* cb = (i < 1024) ? cb_s : cb_x;
    double* cn = (i < 1024) ? cn_s : cn_x;
    int c = i & 1023;
    double s = 0.0;
    for (int k = 0; k < 64; ++k) { double v = (double)cb[c * 64 + k]; s += v * v; }
    cn[c] = s;
}

// ---------------- fused decoder fc+conv1 weights (spectral) ----------------
// Weff[(c*8+l)][d] = sum_{ci,dd valid} w1[c,ci,dd] * dfcw[(ci*8+l+dd-1)][d]
__global__ void k_weff_s(const float* __restrict__ w1, const float* __restrict__ b1,
                         const float* __restrict__ dfcw, const float* __restrict__ dfcb,
                         float* __restrict__ weff, float* __restrict__ beff) {
    int idx = blockIdx.x * 256 + threadIdx.x;
    if (idx >= 128 * 64) return;
    int o = idx >> 6, d = idx & 63;
    int c = o >> 3, l = o & 7;
    double acc = 0.0;
    for (int ci = 0; ci < 16; ++ci)
        for (int dd = 0; dd < 3; ++dd) {
            int ll = l + dd - 1;
            if (ll < 0 || ll > 7) continue;
            acc += (double)w1[(c * 16 + ci) * 3 + dd] * (double)dfcw[(ci * 8 + ll) * 64 + d];
        }
    weff[o * 64 + d] = (float)acc;
    if (d == 0) {
        double bb = (double)b1[c];
        for (int ci = 0; ci < 16; ++ci)
            for (int dd = 0; dd < 3; ++dd) {
                int ll = l + dd - 1;
                if (ll < 0 || ll > 7) continue;
                bb += (double)w1[(c * 16 + ci) * 3 + dd] * (double)dfcb[ci * 8 + ll];
            }
        beff[o] = (float)bb;
    }
}

// ---------------- fused decoder fc+conv1 weights (spatial) ----------------
__global__ void k_weff_x(const float* __restrict__ w1, const float* __restrict__ b1,
                         const float* __restrict__ dfcw, const float* __restrict__ dfcb,
                         float* __restrict__ weff, float* __restrict__ beff) {
    int idx = blockIdx.x * 256 + threadIdx.x;
    if (idx >= 144 * 64) return;
    int o = idx >> 6, d = idx & 63;
    int c = o / 9, p = o - c * 9;
    int i = p / 3, j = p % 3;
    double acc = 0.0;
    for (int ci = 0; ci < 16; ++ci)
        for (int di = 0; di < 3; ++di) {
            int ii = i + di - 1; if (ii < 0 || ii > 2) continue;
            for (int dj = 0; dj < 3; ++dj) {
                int jj = j + dj - 1; if (jj < 0 || jj > 2) continue;
                acc += (double)w1[((c * 16 + ci) * 3 + di) * 3 + dj]
                     * (double)dfcw[(ci * 9 + ii * 3 + jj) * 64 + d];
            }
        }
    weff[o * 64 + d] = (float)acc;
    if (d == 0) {
        double bb = (double)b1[c];
        for (int ci = 0; ci < 16; ++ci)
            for (int di = 0; di < 3; ++di) {
                int ii = i + di - 1; if (ii < 0 || ii > 2) continue;
                for (int dj = 0; dj < 3; ++dj) {
                    int jj = j + dj - 1; if (jj < 0 || jj > 2) continue;
                    bb += (double)w1[((c * 16 + ci) * 3 + di) * 3 + dj]
                        * (double)dfcb[ci * 9 + ii * 3 + jj];
                }
            }
        beff[o] = (float)bb;
    }
}

// ---------------- spectral encoder: 16 tokens/block, lane = (token, channel) ----------------
__global__ void __launch_bounds__(256) k_spec_enc(
    const float* __restrict__ cubes,
    const float* __restrict__ w1, const float* __restrict__ b1,
    const float* __restrict__ w2, const float* __restrict__ b2,
    const float* __restrict__ fcw, const float* __restrict__ fcb,
    float* __restrict__ z_out)
{
    __shared__ float S[16 * 8];       // spec means
    __shared__ float A[16 * 136];     // h1, token stride 136 (mod32=8)
    __shared__ float Bb[16 * 136];    // h2
    int tid = threadIdx.x;
    int t = tid >> 4, c = tid & 15;
    if (tid < 128) {
        int tk = tid >> 3, f = tid & 7;
        const float* cu = cubes + ((size_t)blockIdx.x * 16 + tk) * 72 + f * 9;
        float s = 0.f;
        #pragma unroll
        for (int k = 0; k < 9; ++k) s += cu[k];
        S[tk * 8 + f] = s * (1.0f / 9.0f);
    }
    __syncthreads();
    // conv1 1->16
    {
        float s0[8];
        *(float4*)&s0[0] = *(const float4*)&S[t * 8];
        *(float4*)&s0[4] = *(const float4*)&S[t * 8 + 4];
        float wa = w1[c * 3 + 0], wb = w1[c * 3 + 1], wc = w1[c * 3 + 2], bb = b1[c];
        #pragma unroll
        for (int l = 0; l < 8; ++l) {
            float v = fmaf(wb, s0[l], bb);
            if (l > 0) v = fmaf(wa, s0[l - 1], v);
            if (l < 7) v = fmaf(wc, s0[l + 1], v);
            A[t * 136 + c * 8 + l] = gelu_f(v);
        }
    }
    __syncthreads();
    // conv2 16->16
    {
        float acc[8];
        #pragma unroll
        for (int l = 0; l < 8; ++l) acc[l] = b2[c];
        for (int ci = 0; ci < 16; ++ci) {
            float r[8];
            *(float4*)&r[0] = *(const float4*)&A[t * 136 + ci * 8];
            *(float4*)&r[4] = *(const float4*)&A[t * 136 + ci * 8 + 4];
            float wa = w2[(c * 16 + ci) * 3 + 0], wb = w2[(c * 16 + ci) * 3 + 1], wc = w2[(c * 16 + ci) * 3 + 2];
            #pragma unroll
            for (int l = 0; l < 8; ++l) {
                if (l > 0) acc[l] = fmaf(wa, r[l - 1], acc[l]);
                acc[l] = fmaf(wb, r[l], acc[l]);
                if (l < 7) acc[l] = fmaf(wc, r[l + 1], acc[l]);
            }
        }
        #pragma unroll
        for (int l = 0; l < 8; ++l) Bb[t * 136 + c * 8 + l] = gelu_f(acc[l]);
    }
    __syncthreads();
    // fc 128->64: lane computes d = c*4 .. c*4+3
    {
        float z0 = fcb[c * 4 + 0], z1 = fcb[c * 4 + 1], z2 = fcb[c * 4 + 2], z3 = fcb[c * 4 + 3];
        for (int ci = 0; ci < 16; ++ci) {
            float r[8];
            *(float4*)&r[0] = *(const float4*)&Bb[t * 136 + ci * 8];
            *(float4*)&r[4] = *(const float4*)&Bb[t * 136 + ci * 8 + 4];
            #pragma unroll
            for (int l = 0; l < 8; ++l) {
                int e = ci * 8 + l;
                z0 = fmaf(fcw[(c * 4 + 0) * 128 + e], r[l], z0);
                z1 = fmaf(fcw[(c * 4 + 1) * 128 + e], r[l], z1);
                z2 = fmaf(fcw[(c * 4 + 2) * 128 + e], r[l], z2);
                z3 = fmaf(fcw[(c * 4 + 3) * 128 + e], r[l], z3);
            }
        }
        *(float4*)(z_out + ((size_t)blockIdx.x * 16 + t) * 64 + c * 4) = make_float4(z0, z1, z2, z3);
    }
}

// ---------------- spatial encoder ----------------
__global__ void __launch_bounds__(256) k_spat_enc(
    const float* __restrict__ cubes,
    const float* __restrict__ w1, const float* __restrict__ b1,
    const float* __restrict__ w2, const float* __restrict__ b2,
    const float* __restrict__ fcw, const float* __restrict__ fcb,
    float* __restrict__ z_out)
{
    __shared__ float A[16 * 200];     // input [8][12] padded, later h2 [16][12]; stride 200 (mod32=8)
    __shared__ float Bb[16 * 200];    // h1 [16][12]
    int tid = threadIdx.x;
    int t = tid >> 4, c = tid & 15;
    for (int u = tid; u < 1152; u += 256) {
        int tk = u / 72, e = u - tk * 72;
        int ci = e / 9, p = e - ci * 9;
        A[tk * 200 + ci * 12 + p] = cubes[(size_t)blockIdx.x * 1152 + u];
    }
    __syncthreads();
    // conv1 8->16
    {
        float acc[9];
        #pragma unroll
        for (int p = 0; p < 9; ++p) acc[p] = b1[c];
        for (int ci = 0; ci < 8; ++ci) {
            float r[12];
            *(float4*)&r[0] = *(const float4*)&A[t * 200 + ci * 12];
            *(float4*)&r[4] = *(const float4*)&A[t * 200 + ci * 12 + 4];
            *(float4*)&r[8] = *(const float4*)&A[t * 200 + ci * 12 + 8];
            const float* w = w1 + (c * 8 + ci) * 9;
            #pragma unroll
            for (int p = 0; p < 9; ++p) {
                int i = p / 3, j = p % 3;
                #pragma unroll
                for (int di = 0; di < 3; ++di) {
                    int ii = i + di - 1; if (ii < 0 || ii > 2) continue;
                    #pragma unroll
                    for (int dj = 0; dj < 3; ++dj) {
                        int jj = j + dj - 1; if (jj < 0 || jj > 2) continue;
                        acc[p] = fmaf(w[di * 3 + dj], r[ii * 3 + jj], acc[p]);
                    }
                }
            }
        }
        #pragma unroll
        for (int p = 0; p < 9; ++p) Bb[t * 200 + c * 12 + p] = gelu_f(acc[p]);
    }
    __syncthreads();
    // conv2 16->16 (reads Bb, writes A — all conv1 A-reads completed before barrier)
    {
        float acc[9];
        #pragma unroll
        for (int p = 0; p < 9; ++p) acc[p] = b2[c];
        for (int ci = 0; ci < 16; ++ci) {
            float r[12];
            *(float4*)&r[0] = *(const float4*)&Bb[t * 200 + ci * 12];
            *(float4*)&r[4] = *(const float4*)&Bb[t * 200 + ci * 12 + 4];
            *(float4*)&r[8] = *(const float4*)&Bb[t * 200 + ci * 12 + 8];
            const float* w = w2 + (c * 16 + ci) * 9;
            #pragma unroll
            for (int p = 0; p < 9; ++p) {
                int i = p / 3, j = p % 3;
                #pragma unroll
                for (int di = 0; di < 3; ++di) {
                    int ii = i + di - 1; if (ii < 0 || ii > 2) continue;
                    #pragma unroll
                    for (int dj = 0; dj < 3; ++dj) {
                        int jj = j + dj - 1; if (jj < 0 || jj > 2) continue;
                        acc[p] = fmaf(w[di * 3 + dj], r[ii * 3 + jj], acc[p]);
                    }
                }
            }
        }
        __syncthreads();
        #pragma unroll
        for (int p = 0; p < 9; ++p) A[t * 200 + c * 12 + p] = gelu_f(acc[p]);
    }
    __syncthreads();
    // fc 144->64
    {
        float z0 = fcb[c * 4 + 0], z1 = fcb[c * 4 + 1], z2 = fcb[c * 4 + 2], z3 = fcb[c * 4 + 3];
        for (int ci = 0; ci < 16; ++ci) {
            float r[12];
            *(float4*)&r[0] = *(const float4*)&A[t * 200 + ci * 12];
            *(float4*)&r[4] = *(const float4*)&A[t * 200 + ci * 12 + 4];
            *(float4*)&r[8] = *(const float4*)&A[t * 200 + ci * 12 + 8];
            #pragma unroll
            for (int p = 0; p < 9; ++p) {
                int e = ci * 9 + p;
                z0 = fmaf(fcw[(c * 4 + 0) * 144 + e], r[p], z0);
                z1 = fmaf(fcw[(c * 4 + 1) * 144 + e], r[p], z1);
                z2 = fmaf(fcw[(c * 4 + 2) * 144 + e], r[p], z2);
                z3 = fmaf(fcw[(c * 4 + 3) * 144 + e], r[p], z3);
            }
        }
        *(float4*)(z_out + ((size_t)blockIdx.x * 16 + t) * 64 + c * 4) = make_float4(z0, z1, z2, z3);
    }
}

// ---------------- VQ: 64 tokens/block, 4 waves each scan 256 codes ----------------
__global__ void __launch_bounds__(256) k_vq(
    float* __restrict__ emb, const float* __restrict__ cb,
    const double* __restrict__ cn,
    float* __restrict__ idx_out, int* __restrict__ hist,
    double* __restrict__ partial)
{
    __shared__ double pbest[4][64];
    __shared__ int pidx[4][64];
    __shared__ int lh[1024];
    int tid = threadIdx.x;
    int w = tid >> 6, l = tid & 63;
    for (int u = tid; u < 1024; u += 256) lh[u] = 0;
    size_t n = (size_t)blockIdx.x * 64 + l;
    float z[64];
    {
        const float4* zp = (const float4*)(emb + n * 64);
        #pragma unroll
        for (int k = 0; k < 16; ++k) *(float4*)&z[k * 4] = zp[k];
    }
    double best = 1e300; int bi = w * 256;
    for (int c = w * 256; c < w * 256 + 256; ++c) {
        const float* cr = cb + ((size_t)c << 6);   // uniform address -> scalar loads
        float d0 = 0.f, d1 = 0.f, d2 = 0.f, d3 = 0.f;
        #pragma unroll
        for (int k = 0; k < 64; k += 4) {
            d0 = fmaf(z[k + 0], cr[k + 0], d0);
            d1 = fmaf(z[k + 1], cr[k + 1], d1);
            d2 = fmaf(z[k + 2], cr[k + 2], d2);
            d3 = fmaf(z[k + 3], cr[k + 3], d3);
        }
        float dot = (d0 + d1) + (d2 + d3);
        double dd = cn[c] - 2.0 * (double)dot;
        if (dd < best) { best = dd; bi = c; }      // strict <: first-index within chunk
    }
    pbest[w][l] = best; pidx[w][l] = bi;
    __syncthreads();
    if (w == 0) {
        double b = pbest[0][l]; int bj = pidx[0][l];
        #pragma unroll
        for (int q = 1; q < 4; ++q) {              // ascending chunks: strict < keeps first index
            double d = pbest[q][l];
            if (d < b) { b = d; bj = pidx[q][l]; }
        }
        idx_out[n] = (float)bj;
        float qv[64];
        {
            const float4* cq = (const float4*)(cb + ((size_t)bj << 6));
            #pragma unroll
            for (int k = 0; k < 16; ++k) *(float4*)&qv[k * 4] = cq[k];
        }
        float vs = 0.f;
        #pragma unroll
        for (int k = 0; k < 64; ++k) { float df = z[k] - qv[k]; vs = fmaf(df, df, vs); }
        float4* zo = (float4*)(emb + n * 64);
        #pragma unroll
        for (int k = 0; k < 16; ++k) zo[k] = *(float4*)&qv[k * 4];
        atomicAdd(&lh[bj], 1);
        double s = (double)vs;
        #pragma unroll
        for (int o = 32; o > 0; o >>= 1) s += __shfl_down(s, o);
        if (l == 0) partial[blockIdx.x] = s;
    }
    __syncthreads();
    for (int u = tid; u < 1024; u += 256) if (lh[u] > 0) atomicAdd(&hist[u], lh[u]);
}

// ---------------- spectral decoder (fused fc+conv1) + recon loss ----------------
__global__ void __launch_bounds__(256) k_spec_dec(
    const float* __restrict__ emb, const float* __restrict__ cubes,
    const float* __restrict__ weff, const float* __restrict__ beff,
    const float* __restrict__ w2, const float* __restrict__ b2,
    double* __restrict__ partial)
{
    __shared__ float Z[16 * 72];
    __shared__ float Bb[16 * 136];
    __shared__ float S[16 * 8];
    __shared__ double wred[4];
    int tid = threadIdx.x;
    int t = tid >> 4, c = tid & 15;
    {
        int tk = tid >> 4, dq = tid & 15;
        *(float4*)&Z[tk * 72 + dq * 4] =
            *(const float4*)(emb + (size_t)blockIdx.x * 1024 + (size_t)tid * 4);
    }
    if (tid < 128) {
        int tk = tid >> 3, f = tid & 7;
        const float* cu = cubes + ((size_t)blockIdx.x * 16 + tk) * 72 + f * 9;
        float s = 0.f;
        #pragma unroll
        for (int k = 0; k < 9; ++k) s += cu[k];
        S[tk * 8 + f] = s * (1.0f / 9.0f);
    }
    __syncthreads();
    float zr[64];
    #pragma unroll
    for (int k = 0; k < 16; ++k) *(float4*)&zr[k * 4] = *(const float4*)&Z[t * 72 + k * 4];
    #pragma unroll
    for (int l = 0; l < 8; ++l) {
        int o = c * 8 + l;
        const float* wr = weff + o * 64;
        float a0 = 0.f, a1 = 0.f, a2 = 0.f, a3 = 0.f;
        #pragma unroll
        for (int k = 0; k < 64; k += 4) {
            a0 = fmaf(wr[k + 0], zr[k + 0], a0);
            a1 = fmaf(wr[k + 1], zr[k + 1], a1);
            a2 = fmaf(wr[k + 2], zr[k + 2], a2);
            a3 = fmaf(wr[k + 3], zr[k + 3], a3);
        }
        Bb[t * 136 + c * 8 + l] = gelu_f(beff[o] + ((a0 + a1) + (a2 + a3)));
    }
    __syncthreads();
    // conv2 16->1 + loss: lane = (h, pos); ci range h*8..h*8+7
    float acc2 = 0.f;
    {
        int h = c >> 3, pos = c & 7;
        float a = (h == 0) ? b2[0] : 0.f;
        for (int ci = h * 8; ci < h * 8 + 8; ++ci) {
            const float* w = w2 + ci * 3;
            const float* hb = &Bb[t * 136 + ci * 8];
            if (pos > 0) a = fmaf(w[0], hb[pos - 1], a);
            a = fmaf(w[1], hb[pos], a);
            if (pos < 7) a = fmaf(w[2], hb[pos + 1], a);
        }
        a += __shfl_xor(a, 8);
        if (h == 0) { float df = a - S[t * 8 + pos]; acc2 = df * df; }
    }
    double s = (double)acc2;
    #pragma unroll
    for (int o = 32; o > 0; o >>= 1) s += __shfl_down(s, o);
    if ((tid & 63) == 0) wred[tid >> 6] = s;
    __syncthreads();
    if (tid == 0) partial[blockIdx.x] = wred[0] + wred[1] + wred[2] + wred[3];
}

// ---------------- spatial decoder (fused fc+conv1) + recon loss ----------------
__global__ void __launch_bounds__(256) k_spat_dec(
    const float* __restrict__ emb, const float* __restrict__ cubes,
    const float* __restrict__ weff, const float* __restrict__ beff,
    const float* __restrict__ w2, const float* __restrict__ b2,
    double* __restrict__ partial)
{
    __shared__ float Z[16 * 72];
    __shared__ float H[16 * 200];
    __shared__ float T[16 * 104];
    __shared__ double wred[4];
    int tid = threadIdx.x;
    int t = tid >> 4, c = tid & 15;
    {
        int tk = tid >> 4, dq = tid & 15;
        *(float4*)&Z[tk * 72 + dq * 4] =
            *(const float4*)(emb + (size_t)blockIdx.x * 1024 + (size_t)tid * 4);
    }
    for (int u = tid; u < 1152; u += 256) {
        int tk = u / 72, e = u - tk * 72;
        int ci = e / 9, p = e - ci * 9;
        T[tk * 104 + ci * 12 + p] = cubes[(size_t)blockIdx.x * 1152 + u];
    }
    __syncthreads();
    float zr[64];
    #pragma unroll
    for (int k = 0; k < 16; ++k) *(float4*)&zr[k * 4] = *(const float4*)&Z[t * 72 + k * 4];
    #pragma unroll
    for (int l = 0; l < 9; ++l) {
        int o = c * 9 + l;
        const float* wr = weff + o * 64;
        float a0 = 0.f, a1 = 0.f, a2 = 0.f, a3 = 0.f;
        #pragma unroll
        for (int k = 0; k < 64; k += 4) {
            a0 = fmaf(wr[k + 0], zr[k + 0], a0);
            a1 = fmaf(wr[k + 1], zr[k + 1], a1);
            a2 = fmaf(wr[k + 2], zr[k + 2], a2);
            a3 = fmaf(wr[k + 3], zr[k + 3], a3);
        }
        H[t * 200 + c * 12 + l] = gelu_f(beff[o] + ((a0 + a1) + (a2 + a3)));
    }
    __syncthreads();
    // conv2 16->8 + loss: lane = (co, h); ci range h*8..h*8+7; pair-sum via shfl_xor(1)
    float acc2 = 0.f;
    {
        int co = c >> 1, h = c & 1;
        float accp[9];
        #pragma unroll
        for (int p = 0; p < 9; ++p) accp[p] = (h == 0) ? b2[co] : 0.f;
        for (int ci = h * 8; ci < h * 8 + 8; ++ci) {
            float r[12];
            *(float4*)&r[0] = *(const float4*)&H[t * 200 + ci * 12];
            *(float4*)&r[4] = *(const float4*)&H[t * 200 + ci * 12 + 4];
            *(float4*)&r[8] = *(const float4*)&H[t * 200 + ci * 12 + 8];
            const float* w = w2 + (co * 16 + ci) * 9;
            #pragma unroll
            for (int p = 0; p < 9; ++p) {
                int i = p / 3, j = p % 3;
                #pragma unroll
                for (int di = 0; di < 3; ++di) {
                    int ii = i + di - 1; if (ii < 0 || ii > 2) continue;
                    #pragma unroll
                    for (int dj = 0; dj < 3; ++dj) {
                        int jj = j + dj - 1; if (jj < 0 || jj > 2) continue;
                        accp[p] = fmaf(w[di * 3 + dj], r[ii * 3 + jj], accp[p]);
                    }
                }
            }
        }
        #pragma unroll
        for (int p = 0; p < 9; ++p) {
            float tot = accp[p] + __shfl_xor(accp[p], 1);
            if (h == 0) { float df = tot - T[t * 104 + co * 12 + p]; acc2 = fmaf(df, df, acc2); }
        }
    }
    double s = (double)acc2;
    #pragma unroll
    for (int o = 32; o > 0; o >>= 1) s += __shfl_down(s, o);
    if ((tid & 63) == 0) wred[tid >> 6] = s;
    __syncthreads();
    if (tid == 0) partial[blockIdx.x] = wred[0] + wred[1] + wred[2] + wred[3];
}

// ---------------- finalize scalars ----------------
__global__ void __launch_bounds__(256) k_final(
    const double* __restrict__ p_vq_s, const double* __restrict__ p_vq_x,
    const double* __restrict__ p_rec_s, const double* __restrict__ p_rec_x,
    const int* __restrict__ hist_s, const int* __restrict__ hist_x,
    const int* __restrict__ rr,
    float* __restrict__ outscal)
{
    __shared__ double wred[4];
    int tid = threadIdx.x;
    auto bred = [&](double v) -> double {
        #pragma unroll
        for (int o = 32; o > 0; o >>= 1) v += __shfl_down(v, o);
        __syncthreads();
        if ((tid & 63) == 0) wred[tid >> 6] = v;
        __syncthreads();
        return wred[0] + wred[1] + wred[2] + wred[3];
    };
    double a;
    a = 0; for (int t = tid; t < 1152; t += 256) a += p_vq_s[t];
    double vq_s = bred(a);
    a = 0; for (int t = tid; t < 1152; t += 256) a += p_vq_x[t];
    double vq_x = bred(a);
    a = 0; for (int t = tid; t < 4608; t += 256) a += p_rec_s[t];
    double rec_s = bred(a);
    a = 0; for (int t = tid; t < 4608; t += 256) a += p_rec_x[t];
    double rec_x = bred(a);
    a = 0;
    for (int t = tid; t < 1024; t += 256) {
        double cnt = (double)hist_s[t];
        if (cnt > 0.0) { double p = cnt / (double)NTOK; a += p * log(p + 1e-10); }
    }
    double ent_s = bred(a);
    a = 0;
    for (int t = tid; t < 1024; t += 256) {
        double cnt = (double)hist_x[t];
        if (cnt > 0.0) { double p = cnt / (double)NTOK; a += p * log(p + 1e-10); }
    }
    double ent_x = bred(a);
    if (tid == 0) {
        double total = 0.25 * (vq_s / 4718592.0 + vq_x / 4718592.0);
        double rec = (rr[0] != 0) ? (rec_s / 589824.0 + rec_x / 5308416.0) : 0.0;
        outscal[0] = (float)total;
        outscal[1] = (float)exp(-ent_s);
        outscal[2] = (float)exp(-ent_x);
        outscal[3] = (float)rec;
    }
}

extern "C" void kernel_launch(void* const* d_in, const int* in_sizes, int n_in,
                              void* d_out, int out_size, void* d_ws, size_t ws_size,
                              hipStream_t stream)
{
    const float* cubes  = (const float*)d_in[0];
    const float* s_w1   = (const float*)d_in[1];
    const float* s_b1   = (const float*)d_in[2];
    const float* s_w2   = (const float*)d_in[3];
    const float* s_b2   = (const float*)d_in[4];
    const float* s_fcw  = (const float*)d_in[5];
    const float* s_fcb  = (const float*)d_in[6];
    const float* cb_s   = (const float*)d_in[7];
    const float* s_dfcw = (const float*)d_in[8];
    const float* s_dfcb = (const float*)d_in[9];
    const float* s_dw1  = (const float*)d_in[10];
    const float* s_db1  = (const float*)d_in[11];
    const float* s_dw2  = (const float*)d_in[12];
    const float* s_db2  = (const float*)d_in[13];
    const float* x_w1   = (const float*)d_in[14];
    const float* x_b1   = (const float*)d_in[15];
    const float* x_w2   = (const float*)d_in[16];
    const float* x_b2   = (const float*)d_in[17];
    const float* x_fcw  = (const float*)d_in[18];
    const float* x_fcb  = (const float*)d_in[19];
    const float* cb_x   = (const float*)d_in[20];
    const float* x_dfcw = (const float*)d_in[21];
    const float* x_dfcb = (const float*)d_in[22];
    const float* x_dw1  = (const float*)d_in[23];
    const float* x_db1  = (const float*)d_in[24];
    const float* x_dw2  = (const float*)d_in[25];
    const float* x_db2  = (const float*)d_in[26];
    const int*   rr     = (const int*)d_in[27];

    float* out   = (float*)d_out;
    float* emb_s = out;                       // [N,64]
    float* emb_x = out + 4718592;             // [N,64]
    float* kidx  = out + 9437184;             // [N]
    float* midx  = out + 9510912;             // [N]
    float* scal  = out + 9584640;             // [4]

    char* ws = (char*)d_ws;
    int*    hist_s  = (int*)(ws + 0);
    int*    hist_x  = (int*)(ws + 4096);
    double* cn_s    = (double*)(ws + 8192);
    double* cn_x    = (double*)(ws + 16384);
    double* p_vq_s  = (double*)(ws + 24576);   // 1152 doubles
    double* p_vq_x  = (double*)(ws + 33792);   // 1152
    double* p_rec_s = (double*)(ws + 43008);   // 4608
    double* p_rec_x = (double*)(ws + 79872);   // 4608
    float*  weff_s  = (float*)(ws + 116736);   // 128*64
    float*  beff_s  = (float*)(ws + 149504);   // 128
    float*  weff_x  = (float*)(ws + 150016);   // 144*64
    float*  beff_x  = (float*)(ws + 186880);   // 144

    hipMemsetAsync(d_ws, 0, 8192, stream);     // zero histograms
    k_norms<<<16, 128, 0, stream>>>(cb_s, cb_x, cn_s, cn_x);
    k_weff_s<<<32, 256, 0, stream>>>(s_dw1, s_db1, s_dfcw, s_dfcb, weff_s, beff_s);
    k_weff_x<<<36, 256, 0, stream>>>(x_dw1, x_db1, x_dfcw, x_dfcb, weff_x, beff_x);
    k_spec_enc<<<4608, 256, 0, stream>>>(cubes, s_w1, s_b1, s_w2, s_b2, s_fcw, s_fcb, emb_s);
    k_spat_enc<<<4608, 256, 0, stream>>>(cubes, x_w1, x_b1, x_w2, x_b2, x_fcw, x_fcb, emb_x);
    k_vq<<<1152, 256, 0, stream>>>(emb_s, cb_s, cn_s, kidx, hist_s, p_vq_s);
    k_vq<<<1152, 256, 0, stream>>>(emb_x, cb_x, cn_x, midx, hist_x, p_vq_x);
    k_spec_dec<<<4608, 256, 0, stream>>>(emb_s, cubes, weff_s, beff_s, s_dw2, s_db2, p_rec_s);
    k_spat_dec<<<4608, 256, 0, stream>>>(emb_x, cubes, weff_x, beff_x, x_dw2, x_db2, p_rec_x);
    k_final<<<1, 256, 0, stream>>>(p_vq_s, p_vq_x, p_rec_s, p_rec_x, hist_s, hist_x, rr, scal);
}

// Round 3
// 1078.257 us; speedup vs baseline: 2.6036x; 2.4756x over previous
//
#include <hip/hip_runtime.h>
#include <math.h>

#define NTOK 73728

__device__ __forceinline__ float gelu_f(float x) {
    return 0.5f * x * (1.0f + erff(x * 0.70710678118654752440f));
}

// ---------------- codebook norms in f64 ----------------
__global__ void k_norms(const float* __restrict__ cb_s, const float* __restrict__ cb_x,
                        double* __restrict__ cn_s, double* __restrict__ cn_x) {
    int i = blockIdx.x * blockDim.x + threadIdx.x;
    if (i >= 2048) return;
    const float* cb = (i < 1024) ? cb_s : cb_x;
    double* cn = (i < 1024) ? cn_s : cn_x;
    int c = i & 1023;
    double s = 0.0;
    for (int k = 0; k < 64; ++k) { double v = (double)cb[c * 64 + k]; s += v * v; }
    cn[c] = s;
}

// ---------------- generic 64xE transpose: dst[e*64+d] = src[d*E+e] ----------------
__global__ void k_transpose(const float* __restrict__ src, float* __restrict__ dst, int E) {
    int i = blockIdx.x * 256 + threadIdx.x;
    if (i >= 64 * E) return;
    int e = i >> 6, d = i & 63;
    dst[i] = src[d * E + e];
}

// ---------------- fused decoder fc+conv1 weights (spectral), TRANSPOSED ----------------
// weffT[d*132 + o] = sum w1[c,ci,dd]*dfcw[(ci*8+ll)][d],  o = c*8+l
__global__ void k_weff_s(const float* __restrict__ w1, const float* __restrict__ b1,
                         const float* __restrict__ dfcw, const float* __restrict__ dfcb,
                         float* __restrict__ weffT, float* __restrict__ beff) {
    int idx = blockIdx.x * 256 + threadIdx.x;
    if (idx >= 128 * 64) return;
    int o = idx >> 6, d = idx & 63;
    int c = o >> 3, l = o & 7;
    double acc = 0.0;
    for (int ci = 0; ci < 16; ++ci)
        for (int dd = 0; dd < 3; ++dd) {
            int ll = l + dd - 1;
            if (ll < 0 || ll > 7) continue;
            acc += (double)w1[(c * 16 + ci) * 3 + dd] * (double)dfcw[(ci * 8 + ll) * 64 + d];
        }
    weffT[d * 132 + o] = (float)acc;
    if (o < 4) weffT[d * 132 + 128 + o] = 0.f;
    if (d == 0) {
        double bb = (double)b1[c];
        for (int ci = 0; ci < 16; ++ci)
            for (int dd = 0; dd < 3; ++dd) {
                int ll = l + dd - 1;
                if (ll < 0 || ll > 7) continue;
                bb += (double)w1[(c * 16 + ci) * 3 + dd] * (double)dfcb[ci * 8 + ll];
            }
        beff[o] = (float)bb;
    }
}

// ---------------- fused decoder fc+conv1 weights (spatial), TRANSPOSED ----------------
__global__ void k_weff_x(const float* __restrict__ w1, const float* __restrict__ b1,
                         const float* __restrict__ dfcw, const float* __restrict__ dfcb,
                         float* __restrict__ weffT, float* __restrict__ beff) {
    int idx = blockIdx.x * 256 + threadIdx.x;
    if (idx >= 144 * 64) return;
    int o = idx >> 6, d = idx & 63;
    int c = o / 9, p = o - c * 9;
    int i = p / 3, j = p % 3;
    double acc = 0.0;
    for (int ci = 0; ci < 16; ++ci)
        for (int di = 0; di < 3; ++di) {
            int ii = i + di - 1; if (ii < 0 || ii > 2) continue;
            for (int dj = 0; dj < 3; ++dj) {
                int jj = j + dj - 1; if (jj < 0 || jj > 2) continue;
                acc += (double)w1[((c * 16 + ci) * 3 + di) * 3 + dj]
                     * (double)dfcw[(ci * 9 + ii * 3 + jj) * 64 + d];
            }
        }
    weffT[d * 148 + o] = (float)acc;
    if (o < 4) weffT[d * 148 + 144 + o] = 0.f;
    if (d == 0) {
        double bb = (double)b1[c];
        for (int ci = 0; ci < 16; ++ci)
            for (int di = 0; di < 3; ++di) {
                int ii = i + di - 1; if (ii < 0 || ii > 2) continue;
                for (int dj = 0; dj < 3; ++dj) {
                    int jj = j + dj - 1; if (jj < 0 || jj > 2) continue;
                    bb += (double)w1[((c * 16 + ci) * 3 + di) * 3 + dj]
                        * (double)dfcb[ci * 9 + ii * 3 + jj];
                }
            }
        beff[o] = (float)bb;
    }
}

// ---------------- spectral encoder: 16 tokens/block, lane = (token, channel) ----------------
__global__ void __launch_bounds__(256) k_spec_enc(
    const float* __restrict__ cubes,
    const float* __restrict__ w1, const float* __restrict__ b1,
    const float* __restrict__ w2, const float* __restrict__ b2,
    const float* __restrict__ fcwT, const float* __restrict__ fcb,
    float* __restrict__ z_out)
{
    __shared__ float S[16 * 8];
    __shared__ float A[16 * 136];
    __shared__ float Bb[16 * 136];
    int tid = threadIdx.x;
    int t = tid >> 4, c = tid & 15;
    if (tid < 128) {
        int tk = tid >> 3, f = tid & 7;
        const float* cu = cubes + ((size_t)blockIdx.x * 16 + tk) * 72 + f * 9;
        float s = 0.f;
        #pragma unroll
        for (int k = 0; k < 9; ++k) s += cu[k];
        S[tk * 8 + f] = s * (1.0f / 9.0f);
    }
    __syncthreads();
    // conv1 1->16
    {
        float s0[8];
        *(float4*)&s0[0] = *(const float4*)&S[t * 8];
        *(float4*)&s0[4] = *(const float4*)&S[t * 8 + 4];
        float wa = w1[c * 3 + 0], wb = w1[c * 3 + 1], wc = w1[c * 3 + 2], bb = b1[c];
        #pragma unroll
        for (int l = 0; l < 8; ++l) {
            float v = fmaf(wb, s0[l], bb);
            if (l > 0) v = fmaf(wa, s0[l - 1], v);
            if (l < 7) v = fmaf(wc, s0[l + 1], v);
            A[t * 136 + c * 8 + l] = gelu_f(v);
        }
    }
    __syncthreads();
    // conv2 16->16
    {
        float acc[8];
        #pragma unroll
        for (int l = 0; l < 8; ++l) acc[l] = b2[c];
        for (int ci = 0; ci < 16; ++ci) {
            float r[8];
            *(float4*)&r[0] = *(const float4*)&A[t * 136 + ci * 8];
            *(float4*)&r[4] = *(const float4*)&A[t * 136 + ci * 8 + 4];
            float wa = w2[(c * 16 + ci) * 3 + 0], wb = w2[(c * 16 + ci) * 3 + 1], wc = w2[(c * 16 + ci) * 3 + 2];
            #pragma unroll
            for (int l = 0; l < 8; ++l) {
                if (l > 0) acc[l] = fmaf(wa, r[l - 1], acc[l]);
                acc[l] = fmaf(wb, r[l], acc[l]);
                if (l < 7) acc[l] = fmaf(wc, r[l + 1], acc[l]);
            }
        }
        #pragma unroll
        for (int l = 0; l < 8; ++l) Bb[t * 136 + c * 8 + l] = gelu_f(acc[l]);
    }
    __syncthreads();
    // fc 128->64: uniform-e loop, lane d = 4c..4c+3, coalesced fcwT reads
    {
        float4 zv = make_float4(fcb[c * 4 + 0], fcb[c * 4 + 1], fcb[c * 4 + 2], fcb[c * 4 + 3]);
        #pragma unroll 4
        for (int e = 0; e < 128; ++e) {
            float be = Bb[t * 136 + e];
            float4 wv = *(const float4*)(fcwT + (e << 6) + (c << 2));
            zv.x = fmaf(wv.x, be, zv.x);
            zv.y = fmaf(wv.y, be, zv.y);
            zv.z = fmaf(wv.z, be, zv.z);
            zv.w = fmaf(wv.w, be, zv.w);
        }
        *(float4*)(z_out + ((size_t)blockIdx.x * 16 + t) * 64 + c * 4) = zv;
    }
}

// ---------------- spatial encoder ----------------
__global__ void __launch_bounds__(256) k_spat_enc(
    const float* __restrict__ cubes,
    const float* __restrict__ w1, const float* __restrict__ b1,
    const float* __restrict__ w2, const float* __restrict__ b2,
    const float* __restrict__ fcwT, const float* __restrict__ fcb,
    float* __restrict__ z_out)
{
    __shared__ float A[16 * 200];
    __shared__ float Bb[16 * 200];
    int tid = threadIdx.x;
    int t = tid >> 4, c = tid & 15;
    for (int u = tid; u < 1152; u += 256) {
        int tk = u / 72, e = u - tk * 72;
        int ci = e / 9, p = e - ci * 9;
        A[tk * 200 + ci * 12 + p] = cubes[(size_t)blockIdx.x * 1152 + u];
    }
    __syncthreads();
    // conv1 8->16
    {
        float acc[9];
        #pragma unroll
        for (int p = 0; p < 9; ++p) acc[p] = b1[c];
        for (int ci = 0; ci < 8; ++ci) {
            float r[12];
            *(float4*)&r[0] = *(const float4*)&A[t * 200 + ci * 12];
            *(float4*)&r[4] = *(const float4*)&A[t * 200 + ci * 12 + 4];
            *(float4*)&r[8] = *(const float4*)&A[t * 200 + ci * 12 + 8];
            const float* w = w1 + (c * 8 + ci) * 9;
            #pragma unroll
            for (int p = 0; p < 9; ++p) {
                int i = p / 3, j = p % 3;
                #pragma unroll
                for (int di = 0; di < 3; ++di) {
                    int ii = i + di - 1; if (ii < 0 || ii > 2) continue;
                    #pragma unroll
                    for (int dj = 0; dj < 3; ++dj) {
                        int jj = j + dj - 1; if (jj < 0 || jj > 2) continue;
                        acc[p] = fmaf(w[di * 3 + dj], r[ii * 3 + jj], acc[p]);
                    }
                }
            }
        }
        #pragma unroll
        for (int p = 0; p < 9; ++p) Bb[t * 200 + c * 12 + p] = gelu_f(acc[p]);
    }
    __syncthreads();
    // conv2 16->16
    {
        float acc[9];
        #pragma unroll
        for (int p = 0; p < 9; ++p) acc[p] = b2[c];
        for (int ci = 0; ci < 16; ++ci) {
            float r[12];
            *(float4*)&r[0] = *(const float4*)&Bb[t * 200 + ci * 12];
            *(float4*)&r[4] = *(const float4*)&Bb[t * 200 + ci * 12 + 4];
            *(float4*)&r[8] = *(const float4*)&Bb[t * 200 + ci * 12 + 8];
            const float* w = w2 + (c * 16 + ci) * 9;
            #pragma unroll
            for (int p = 0; p < 9; ++p) {
                int i = p / 3, j = p % 3;
                #pragma unroll
                for (int di = 0; di < 3; ++di) {
                    int ii = i + di - 1; if (ii < 0 || ii > 2) continue;
                    #pragma unroll
                    for (int dj = 0; dj < 3; ++dj) {
                        int jj = j + dj - 1; if (jj < 0 || jj > 2) continue;
                        acc[p] = fmaf(w[di * 3 + dj], r[ii * 3 + jj], acc[p]);
                    }
                }
            }
        }
        __syncthreads();
        #pragma unroll
        for (int p = 0; p < 9; ++p) A[t * 200 + c * 12 + p] = gelu_f(acc[p]);
    }
    __syncthreads();
    // fc 144->64: uniform-e loop, coalesced fcwT
    {
        float4 zv = make_float4(fcb[c * 4 + 0], fcb[c * 4 + 1], fcb[c * 4 + 2], fcb[c * 4 + 3]);
        #pragma unroll 4
        for (int e = 0; e < 144; ++e) {
            int ci = e / 9, p = e - ci * 9;
            float be = A[t * 200 + ci * 12 + p];
            float4 wv = *(const float4*)(fcwT + (e << 6) + (c << 2));
            zv.x = fmaf(wv.x, be, zv.x);
            zv.y = fmaf(wv.y, be, zv.y);
            zv.z = fmaf(wv.z, be, zv.z);
            zv.w = fmaf(wv.w, be, zv.w);
        }
        *(float4*)(z_out + ((size_t)blockIdx.x * 16 + t) * 64 + c * 4) = zv;
    }
}

// ---------------- VQ: 64 tokens/wave, 4 waves each scan 256 codes via SGPR loads ----------------
__global__ void __launch_bounds__(256) k_vq(
    float* __restrict__ emb, const float* __restrict__ cb,
    const double* __restrict__ cn,
    float* __restrict__ idx_out, int* __restrict__ hist,
    double* __restrict__ partial)
{
    __shared__ double pbest[4][64];
    __shared__ int pidx[4][64];
    __shared__ int lh[1024];
    int tid = threadIdx.x;
    int w = tid >> 6, l = tid & 63;
    for (int u = tid; u < 1024; u += 256) lh[u] = 0;
    size_t n = (size_t)blockIdx.x * 64 + l;
    float z[64];
    {
        const float4* zp = (const float4*)(emb + n * 64);
        #pragma unroll
        for (int k = 0; k < 16; ++k) *(float4*)&z[k * 4] = zp[k];
    }
    // force wave-uniform base -> SGPR codebook pointer -> s_load + v_fmac(sgpr)
    int base = __builtin_amdgcn_readfirstlane(w << 8);
    const float* crb = cb + ((size_t)base << 6);
    const double* cnb = cn + base;
    double best = 1e300; int bi = base;
    for (int cc = 0; cc < 256; ++cc) {
        const float* cr = crb + (cc << 6);
        float d0 = 0.f, d1 = 0.f, d2 = 0.f, d3 = 0.f;
        #pragma unroll
        for (int k = 0; k < 64; k += 4) {
            d0 = fmaf(z[k + 0], cr[k + 0], d0);
            d1 = fmaf(z[k + 1], cr[k + 1], d1);
            d2 = fmaf(z[k + 2], cr[k + 2], d2);
            d3 = fmaf(z[k + 3], cr[k + 3], d3);
        }
        float dot = (d0 + d1) + (d2 + d3);
        double dd = cnb[cc] - 2.0 * (double)dot;
        if (dd < best) { best = dd; bi = base + cc; }   // strict <: first-index
    }
    pbest[w][l] = best; pidx[w][l] = bi;
    __syncthreads();
    if (w == 0) {
        double b = pbest[0][l]; int bj = pidx[0][l];
        #pragma unroll
        for (int q = 1; q < 4; ++q) {
            double d = pbest[q][l];
            if (d < b) { b = d; bj = pidx[q][l]; }
        }
        idx_out[n] = (float)bj;
        float qv[64];
        {
            const float4* cq = (const float4*)(cb + ((size_t)bj << 6));
            #pragma unroll
            for (int k = 0; k < 16; ++k) *(float4*)&qv[k * 4] = cq[k];
        }
        float vs = 0.f;
        #pragma unroll
        for (int k = 0; k < 64; ++k) { float df = z[k] - qv[k]; vs = fmaf(df, df, vs); }
        float4* zo = (float4*)(emb + n * 64);
        #pragma unroll
        for (int k = 0; k < 16; ++k) zo[k] = *(float4*)&qv[k * 4];
        atomicAdd(&lh[bj], 1);
        double s = (double)vs;
        #pragma unroll
        for (int o = 32; o > 0; o >>= 1) s += __shfl_down(s, o);
        if (l == 0) partial[blockIdx.x] = s;
    }
    __syncthreads();
    for (int u = tid; u < 1024; u += 256) if (lh[u] > 0) atomicAdd(&hist[u], lh[u]);
}

// ---------------- spectral decoder (coalesced weffT matvec) + recon loss ----------------
__global__ void __launch_bounds__(256) k_spec_dec(
    const float* __restrict__ emb, const float* __restrict__ cubes,
    const float* __restrict__ weffT, const float* __restrict__ beff,
    const float* __restrict__ w2, const float* __restrict__ b2,
    double* __restrict__ partial)
{
    __shared__ float Z[16 * 72];
    __shared__ float Bb[16 * 136];
    __shared__ float S[16 * 8];
    __shared__ double wred[4];
    int tid = threadIdx.x;
    int t = tid >> 4, c = tid & 15;
    {
        int tk = tid >> 4, dq = tid & 15;
        *(float4*)&Z[tk * 72 + dq * 4] =
            *(const float4*)(emb + (size_t)blockIdx.x * 1024 + (size_t)tid * 4);
    }
    if (tid < 128) {
        int tk = tid >> 3, f = tid & 7;
        const float* cu = cubes + ((size_t)blockIdx.x * 16 + tk) * 72 + f * 9;
        float s = 0.f;
        #pragma unroll
        for (int k = 0; k < 9; ++k) s += cu[k];
        S[tk * 8 + f] = s * (1.0f / 9.0f);
    }
    __syncthreads();
    float zr[64];
    #pragma unroll
    for (int k = 0; k < 16; ++k) *(float4*)&zr[k * 4] = *(const float4*)&Z[t * 72 + k * 4];
    // matvec: lane owns o = 4c..4c+3 and 64+4c..64+4c+3; uniform-k loop, coalesced reads
    {
        float4 a0 = make_float4(0.f, 0.f, 0.f, 0.f);
        float4 a1 = make_float4(0.f, 0.f, 0.f, 0.f);
        #pragma unroll 8
        for (int k = 0; k < 64; ++k) {
            float zk = zr[k];
            float4 w0 = *(const float4*)(weffT + k * 132 + (c << 2));
            float4 w1v = *(const float4*)(weffT + k * 132 + 64 + (c << 2));
            a0.x = fmaf(w0.x, zk, a0.x); a0.y = fmaf(w0.y, zk, a0.y);
            a0.z = fmaf(w0.z, zk, a0.z); a0.w = fmaf(w0.w, zk, a0.w);
            a1.x = fmaf(w1v.x, zk, a1.x); a1.y = fmaf(w1v.y, zk, a1.y);
            a1.z = fmaf(w1v.z, zk, a1.z); a1.w = fmaf(w1v.w, zk, a1.w);
        }
        int o0 = c << 2, o1 = 64 + (c << 2);
        float4 g0 = make_float4(gelu_f(a0.x + beff[o0 + 0]), gelu_f(a0.y + beff[o0 + 1]),
                                gelu_f(a0.z + beff[o0 + 2]), gelu_f(a0.w + beff[o0 + 3]));
        float4 g1 = make_float4(gelu_f(a1.x + beff[o1 + 0]), gelu_f(a1.y + beff[o1 + 1]),
                                gelu_f(a1.z + beff[o1 + 2]), gelu_f(a1.w + beff[o1 + 3]));
        *(float4*)&Bb[t * 136 + o0] = g0;
        *(float4*)&Bb[t * 136 + o1] = g1;
    }
    __syncthreads();
    // conv2 16->1 + loss
    float acc2 = 0.f;
    {
        int h = c >> 3, pos = c & 7;
        float a = (h == 0) ? b2[0] : 0.f;
        for (int ci = h * 8; ci < h * 8 + 8; ++ci) {
            const float* w = w2 + ci * 3;
            const float* hb = &Bb[t * 136 + ci * 8];
            if (pos > 0) a = fmaf(w[0], hb[pos - 1], a);
            a = fmaf(w[1], hb[pos], a);
            if (pos < 7) a = fmaf(w[2], hb[pos + 1], a);
        }
        a += __shfl_xor(a, 8);
        if (h == 0) { float df = a - S[t * 8 + pos]; acc2 = df * df; }
    }
    double s = (double)acc2;
    #pragma unroll
    for (int o = 32; o > 0; o >>= 1) s += __shfl_down(s, o);
    if ((tid & 63) == 0) wred[tid >> 6] = s;
    __syncthreads();
    if (tid == 0) partial[blockIdx.x] = wred[0] + wred[1] + wred[2] + wred[3];
}

// ---------------- spatial decoder (coalesced weffT matvec) + recon loss ----------------
__global__ void __launch_bounds__(256) k_spat_dec(
    const float* __restrict__ emb, const float* __restrict__ cubes,
    const float* __restrict__ weffT, const float* __restrict__ beff,
    const float* __restrict__ w2, const float* __restrict__ b2,
    double* __restrict__ partial)
{
    __shared__ float Z[16 * 72];
    __shared__ float H[16 * 200];
    __shared__ float T[16 * 104];
    __shared__ double wred[4];
    int tid = threadIdx.x;
    int t = tid >> 4, c = tid & 15;
    {
        int tk = tid >> 4, dq = tid & 15;
        *(float4*)&Z[tk * 72 + dq * 4] =
            *(const float4*)(emb + (size_t)blockIdx.x * 1024 + (size_t)tid * 4);
    }
    for (int u = tid; u < 1152; u += 256) {
        int tk = u / 72, e = u - tk * 72;
        int ci = e / 9, p = e - ci * 9;
        T[tk * 104 + ci * 12 + p] = cubes[(size_t)blockIdx.x * 1152 + u];
    }
    __syncthreads();
    float zr[64];
    #pragma unroll
    for (int k = 0; k < 16; ++k) *(float4*)&zr[k * 4] = *(const float4*)&Z[t * 72 + k * 4];
    // matvec: lane owns o = 4c + 64j, j=0..2
    {
        float4 a0 = make_float4(0.f, 0.f, 0.f, 0.f);
        float4 a1 = make_float4(0.f, 0.f, 0.f, 0.f);
        float4 a2 = make_float4(0.f, 0.f, 0.f, 0.f);
        #pragma unroll 8
        for (int k = 0; k < 64; ++k) {
            float zk = zr[k];
            float4 w0 = *(const float4*)(weffT + k * 148 + (c << 2));
            float4 w1v = *(const float4*)(weffT + k * 148 + 64 + (c << 2));
            float4 w2v = *(const float4*)(weffT + k * 148 + 128 + (c << 2));
            a0.x = fmaf(w0.x, zk, a0.x); a0.y = fmaf(w0.y, zk, a0.y);
            a0.z = fmaf(w0.z, zk, a0.z); a0.w = fmaf(w0.w, zk, a0.w);
            a1.x = fmaf(w1v.x, zk, a1.x); a1.y = fmaf(w1v.y, zk, a1.y);
            a1.z = fmaf(w1v.z, zk, a1.z); a1.w = fmaf(w1v.w, zk, a1.w);
            a2.x = fmaf(w2v.x, zk, a2.x); a2.y = fmaf(w2v.y, zk, a2.y);
            a2.z = fmaf(w2v.z, zk, a2.z); a2.w = fmaf(w2v.w, zk, a2.w);
        }
        float av[12] = {a0.x, a0.y, a0.z, a0.w, a1.x, a1.y, a1.z, a1.w, a2.x, a2.y, a2.z, a2.w};
        #pragma unroll
        for (int q = 0; q < 12; ++q) {
            int o = (c << 2) + ((q >> 2) << 6) + (q & 3);
            int ch = o / 9, p = o - ch * 9;
            H[t * 200 + ch * 12 + p] = gelu_f(av[q] + beff[o]);
        }
    }
    __syncthreads();
    // conv2 16->8 + loss
    float acc2 = 0.f;
    {
        int co = c >> 1, h = c & 1;
        float accp[9];
        #pragma unroll
        for (int p = 0; p < 9; ++p) accp[p] = (h == 0) ? b2[co] : 0.f;
        for (int ci = h * 8; ci < h * 8 + 8; ++ci) {
            float r[12];
            *(float4*)&r[0] = *(const float4*)&H[t * 200 + ci * 12];
            *(float4*)&r[4] = *(const float4*)&H[t * 200 + ci * 12 + 4];
            *(float4*)&r[8] = *(const float4*)&H[t * 200 + ci * 12 + 8];
            const float* w = w2 + (co * 16 + ci) * 9;
            #pragma unroll
            for (int p = 0; p < 9; ++p) {
                int i = p / 3, j = p % 3;
                #pragma unroll
                for (int di = 0; di < 3; ++di) {
                    int ii = i + di - 1; if (ii < 0 || ii > 2) continue;
                    #pragma unroll
                    for (int dj = 0; dj < 3; ++dj) {
                        int jj = j + dj - 1; if (jj < 0 || jj > 2) continue;
                        accp[p] = fmaf(w[di * 3 + dj], r[ii * 3 + jj], accp[p]);
                    }
                }
            }
        }
        #pragma unroll
        for (int p = 0; p < 9; ++p) {
            float tot = accp[p] + __shfl_xor(accp[p], 1);
            if (h == 0) { float df = tot - T[t * 104 + co * 12 + p]; acc2 = fmaf(df, df, acc2); }
        }
    }
    double s = (double)acc2;
    #pragma unroll
    for (int o = 32; o > 0; o >>= 1) s += __shfl_down(s, o);
    if ((tid & 63) == 0) wred[tid >> 6] = s;
    __syncthreads();
    if (tid == 0) partial[blockIdx.x] = wred[0] + wred[1] + wred[2] + wred[3];
}

// ---------------- finalize scalars ----------------
__global__ void __launch_bounds__(256) k_final(
    const double* __restrict__ p_vq_s, const double* __restrict__ p_vq_x,
    const double* __restrict__ p_rec_s, const double* __restrict__ p_rec_x,
    const int* __restrict__ hist_s, const int* __restrict__ hist_x,
    const int* __restrict__ rr,
    float* __restrict__ outscal)
{
    __shared__ double wred[4];
    int tid = threadIdx.x;
    auto bred = [&](double v) -> double {
        #pragma unroll
        for (int o = 32; o > 0; o >>= 1) v += __shfl_down(v, o);
        __syncthreads();
        if ((tid & 63) == 0) wred[tid >> 6] = v;
        __syncthreads();
        return wred[0] + wred[1] + wred[2] + wred[3];
    };
    double a;
    a = 0; for (int t = tid; t < 1152; t += 256) a += p_vq_s[t];
    double vq_s = bred(a);
    a = 0; for (int t = tid; t < 1152; t += 256) a += p_vq_x[t];
    double vq_x = bred(a);
    a = 0; for (int t = tid; t < 4608; t += 256) a += p_rec_s[t];
    double rec_s = bred(a);
    a = 0; for (int t = tid; t < 4608; t += 256) a += p_rec_x[t];
    double rec_x = bred(a);
    a = 0;
    for (int t = tid; t < 1024; t += 256) {
        double cnt = (double)hist_s[t];
        if (cnt > 0.0) { double p = cnt / (double)NTOK; a += p * log(p + 1e-10); }
    }
    double ent_s = bred(a);
    a = 0;
    for (int t = tid; t < 1024; t += 256) {
        double cnt = (double)hist_x[t];
        if (cnt > 0.0) { double p = cnt / (double)NTOK; a += p * log(p + 1e-10); }
    }
    double ent_x = bred(a);
    if (tid == 0) {
        double total = 0.25 * (vq_s / 4718592.0 + vq_x / 4718592.0);
        double rec = (rr[0] != 0) ? (rec_s / 589824.0 + rec_x / 5308416.0) : 0.0;
        outscal[0] = (float)total;
        outscal[1] = (float)exp(-ent_s);
        outscal[2] = (float)exp(-ent_x);
        outscal[3] = (float)rec;
    }
}

extern "C" void kernel_launch(void* const* d_in, const int* in_sizes, int n_in,
                              void* d_out, int out_size, void* d_ws, size_t ws_size,
                              hipStream_t stream)
{
    const float* cubes  = (const float*)d_in[0];
    const float* s_w1   = (const float*)d_in[1];
    const float* s_b1   = (const float*)d_in[2];
    const float* s_w2   = (const float*)d_in[3];
    const float* s_b2   = (const float*)d_in[4];
    const float* s_fcw  = (const float*)d_in[5];
    const float* s_fcb  = (const float*)d_in[6];
    const float* cb_s   = (const float*)d_in[7];
    const float* s_dfcw = (const float*)d_in[8];
    const float* s_dfcb = (const float*)d_in[9];
    const float* s_dw1  = (const float*)d_in[10];
    const float* s_db1  = (const float*)d_in[11];
    const float* s_dw2  = (const float*)d_in[12];
    const float* s_db2  = (const float*)d_in[13];
    const float* x_w1   = (const float*)d_in[14];
    const float* x_b1   = (const float*)d_in[15];
    const float* x_w2   = (const float*)d_in[16];
    const float* x_b2   = (const float*)d_in[17];
    const float* x_fcw  = (const float*)d_in[18];
    const float* x_fcb  = (const float*)d_in[19];
    const float* cb_x   = (const float*)d_in[20];
    const float* x_dfcw = (const float*)d_in[21];
    const float* x_dfcb = (const float*)d_in[22];
    const float* x_dw1  = (const float*)d_in[23];
    const float* x_db1  = (const float*)d_in[24];
    const float* x_dw2  = (const float*)d_in[25];
    const float* x_db2  = (const float*)d_in[26];
    const int*   rr     = (const int*)d_in[27];

    float* out   = (float*)d_out;
    float* emb_s = out;
    float* emb_x = out + 4718592;
    float* kidx  = out + 9437184;
    float* midx  = out + 9510912;
    float* scal  = out + 9584640;

    char* ws = (char*)d_ws;
    int*    hist_s  = (int*)(ws + 0);        // 4 KB
    int*    hist_x  = (int*)(ws + 4096);     // 4 KB
    double* cn_s    = (double*)(ws + 8192);  // 8 KB
    double* cn_x    = (double*)(ws + 16384); // 8 KB
    double* p_vq_s  = (double*)(ws + 24576); // 1152 d
    double* p_vq_x  = (double*)(ws + 33792); // 1152 d
    double* p_rec_s = (double*)(ws + 43008); // 4608 d
    double* p_rec_x = (double*)(ws + 79872); // 4608 d
    float*  beff_s  = (float*)(ws + 116736); // 128 f
    float*  beff_x  = (float*)(ws + 117248); // 144 f
    float*  weffT_s = (float*)(ws + 117888); // 64*132 f
    float*  weffT_x = (float*)(ws + 151680); // 64*148 f
    float*  fcwT_s  = (float*)(ws + 189568); // 128*64 f
    float*  fcwT_x  = (float*)(ws + 222336); // 144*64 f  (end 259200)

    hipMemsetAsync(d_ws, 0, 8192, stream);
    k_norms<<<16, 128, 0, stream>>>(cb_s, cb_x, cn_s, cn_x);
    k_weff_s<<<32, 256, 0, stream>>>(s_dw1, s_db1, s_dfcw, s_dfcb, weffT_s, beff_s);
    k_weff_x<<<36, 256, 0, stream>>>(x_dw1, x_db1, x_dfcw, x_dfcb, weffT_x, beff_x);
    k_transpose<<<32, 256, 0, stream>>>(s_fcw, fcwT_s, 128);
    k_transpose<<<36, 256, 0, stream>>>(x_fcw, fcwT_x, 144);
    k_spec_enc<<<4608, 256, 0, stream>>>(cubes, s_w1, s_b1, s_w2, s_b2, fcwT_s, s_fcb, emb_s);
    k_spat_enc<<<4608, 256, 0, stream>>>(cubes, x_w1, x_b1, x_w2, x_b2, fcwT_x, x_fcb, emb_x);
    k_vq<<<1152, 256, 0, stream>>>(emb_s, cb_s, cn_s, kidx, hist_s, p_vq_s);
    k_vq<<<1152, 256, 0, stream>>>(emb_x, cb_x, cn_x, midx, hist_x, p_vq_x);
    k_spec_dec<<<4608, 256, 0, stream>>>(emb_s, cubes, weffT_s, beff_s, s_dw2, s_db2, p_rec_s);
    k_spat_dec<<<4608, 256, 0, stream>>>(emb_x, cubes, weffT_x, beff_x, x_dw2, x_db2, p_rec_x);
    k_final<<<1, 256, 0, stream>>>(p_vq_s, p_vq_x, p_rec_s, p_rec_x, hist_s, hist_x, rr, scal);
}